// Round 5
// baseline (568.039 us; speedup 1.0000x reference)
//
#include <hip/hip_runtime.h>

// SpikingNN LIF scan: N=131072 traces x L=401 steps, fp32. Bit-exact vs ref.
//
// Round-3 design ("flat windows"): R1/R2 both hit an identical 200us wall at
// 29% HBM with VALU idle -> diagnosis: VMEM-instruction/segment rate bound
// (832 scalar-dword VMEM instrs/thread, every 128B segment straddling lines
// due to the 1604B row stride). Fix: ALL global I/O is float4, fully
// coalesced AND 16B-aligned contiguous flat spans (the m13 6.3TB/s pattern).
//
//  - Block = 256 traces = contiguous flat span of 256*1604 B (16B-aligned:
//    256*1604 % 16 == 0). Process in 8 windows of RW=32 COMPLETE rows
//    (32*1604 = 51,328 B = 3208 float4, 16B-aligned).
//  - Stage: flat float4 load -> regs (issued one window ahead, T14) ->
//    ds_write_b128. Store: ds_read_b128 -> flat float4 store. One wave
//    instruction = 64 lanes x 16B = 1KB contiguous: single segment.
//  - Compute window g: threads [32g,32g+32) (one half-wave) each scan their
//    full row (401 steps) from LDS in place. LDS row stride 401 floats:
//    401 mod 32 = 17 (odd) -> lane->bank is a permutation, conflict-free.
//  - Scan math identical op-order to reference ((P+s)-0.25, adds/cmp only,
//    no FMA contraction); i==0 folded via P=0, t_rest=-1. Bit-exact.

#define L        401
#define BLKT     256
#define RW       32                       // complete rows per window
#define NWIN     (BLKT / RW)              // 8
#define WIN_F4   ((RW * L) / 4)           // 3208 float4 per window
#define LD_ROUNDS ((WIN_F4 + BLKT - 1) / BLKT)  // 13 (last partial: 136)

__global__ __launch_bounds__(BLKT, 2) void snn_scan_kernel(
    const float* __restrict__ S, float* __restrict__ out)
{
    __shared__ float4 buf4[WIN_F4];       // 51,328 B -> 2 blocks/CU
    float* buf = (float*)buf4;

    const int tid = threadIdx.x;
    const int ts  = blockIdx.x * BLKT;    // first trace of this block

    const float4* __restrict__ S4 = (const float4*)S;
    float4*       __restrict__ O4 = (float4*)out;

    // ---- prologue: stage window 0 (flat, coalesced, aligned) ----
    {
        const int b4 = (ts >> 2) * L;     // float4 index of window start
        float4 pre[LD_ROUNDS];
        #pragma unroll
        for (int k = 0; k < LD_ROUNDS; ++k) {
            const int idx = k * BLKT + tid;
            if (idx < WIN_F4) pre[k] = S4[b4 + idx];
        }
        #pragma unroll
        for (int k = 0; k < LD_ROUNDS; ++k) {
            const int idx = k * BLKT + tid;
            if (idx < WIN_F4) buf4[idx] = pre[k];
        }
    }

    #pragma unroll 1
    for (int g = 0; g < NWIN; ++g) {
        __syncthreads();                  // stage(g) visible to all

        // ---- issue window g+1 loads into regs (overlap with compute) ----
        float4 pre[LD_ROUNDS];
        if (g + 1 < NWIN) {
            const int b4 = ((ts + (g + 1) * RW) >> 2) * L;
            #pragma unroll
            for (int k = 0; k < LD_ROUNDS; ++k) {
                const int idx = k * BLKT + tid;
                if (idx < WIN_F4) pre[k] = S4[b4 + idx];
            }
        }

        // ---- compute: owning half-wave scans its 32 full rows in place ----
        if ((tid >> 5) == g) {
            const int r = tid & 31;
            float* __restrict__ row = &buf[r * L];
            float P = 0.0f, t_rest = -1.0f;   // folds the i==0 branch
            #pragma unroll 1
            for (int ib = 0; ib < 50; ++ib) {
                float sv[8], ov[8];
                #pragma unroll
                for (int j = 0; j < 8; ++j) sv[j] = row[ib * 8 + j];
                #pragma unroll
                for (int j = 0; j < 8; ++j) {
                    const float t = (float)(ib * 8 + j) * 0.125f; // exact
                    float p = (t <= t_rest)
                            ? 0.0f
                            : ((P > -1.0f) ? (P + sv[j]) - 0.25f : 0.0f);
                    const bool spike = (p >= 25.0f);
                    t_rest = spike ? t + 5.0f : t_rest;           // exact
                    p      = spike ? p + 4.0f : p;
                    ov[j] = p;
                    P     = p;
                }
                #pragma unroll
                for (int j = 0; j < 8; ++j) row[ib * 8 + j] = ov[j];
            }
            {   // final step i = 400
                const float t  = 50.0f;
                const float sv = row[400];
                float p = (t <= t_rest)
                        ? 0.0f
                        : ((P > -1.0f) ? (P + sv) - 0.25f : 0.0f);
                if (p >= 25.0f) p += 4.0f;
                row[400] = p;
            }
        }

        __syncthreads();                  // compute(g) results visible

        // ---- store window g (flat, coalesced, aligned) ----
        {
            const int b4 = ((ts + g * RW) >> 2) * L;
            #pragma unroll
            for (int k = 0; k < LD_ROUNDS; ++k) {
                const int idx = k * BLKT + tid;
                if (idx < WIN_F4) O4[b4 + idx] = buf4[idx];
            }
        }

        __syncthreads();                  // all store-side LDS reads done

        // ---- stage window g+1 into LDS ----
        if (g + 1 < NWIN) {
            #pragma unroll
            for (int k = 0; k < LD_ROUNDS; ++k) {
                const int idx = k * BLKT + tid;
                if (idx < WIN_F4) buf4[idx] = pre[k];
            }
        }
    }
}

extern "C" void kernel_launch(void* const* d_in, const int* in_sizes, int n_in,
                              void* d_out, int out_size, void* d_ws, size_t ws_size,
                              hipStream_t stream)
{
    // d_in[0] = Pn (dead in reference), d_in[1] = S
    const float* S   = (const float*)d_in[1];
    float*       out = (float*)d_out;

    snn_scan_kernel<<<(131072 / BLKT), BLKT, 0, stream>>>(S, out);
}

// Round 6
// 510.923 us; speedup vs baseline: 1.1118x; 1.1118x over previous
//
#include <hip/hip_runtime.h>

// SpikingNN LIF scan: N=131072 traces x L=401 steps, fp32. Bit-exact vs ref.
//
// Round-6: deep fire-and-forget prefetch via global_load_lds + counted vmcnt.
// Diagnosis history: R1/R2/R5 all ~2.4 TB/s. R5's WRITE_SIZE=2x proved VGPR
// prefetch spills; R2's ~1KB/wave avg in-flight (compiler recycles landing
// VGPRs with chained vmcnt waits) explains 2.4 TB/s by Little's law
// (need ~8.4KB/CU at 900cy latency for 2.4; want 4x more for ~6 TB/s).
// global_load_lds has NO landing VGPRs: 32 loads/wave stay in flight through
// the whole compute phase; drain is MY counted s_waitcnt vmcnt(32) (T4),
// stores are never drained in-loop.
//
//  - Wave-private: wave owns 64 traces; tile = 64 rows x 32 cols (8KB),
//    double-buffered => 64KB/block, 2 blocks/CU. Zero barriers.
//  - gll constraint: LDS dest is linear (base + lane*4). Layout freedom comes
//    from pre-swizzling the GLOBAL source (m173): slot s=k*64+lane holds
//    element (row=s>>5, col=(s&31)^(row&31)). Full-rank XOR =>
//    every LDS access phase is <=2-way (free):
//      compute read/write (lane l, step j): dword l*32+(j^(l&31)), bank j^(l&31)
//      store read (instr k): dword k*64+lane, bank lane&31
//  - Every lane computes its own trace (full compute parallelism, carry in
//    regs across chunks). Scan math in exact ref op order -> bit-exact.

#define L_STEPS 401
#define NCHUNK  13
#define CHUNK   32
#define BLKT    256
#define SLICE   (64 * CHUNK)          // dwords per wave-slice buffer (8 KB)

typedef const __attribute__((address_space(1))) void* gas1_t;
typedef __attribute__((address_space(3))) void*       las3_t;

__global__ __launch_bounds__(BLKT) void snn_scan_kernel(
    const float* __restrict__ S, float* __restrict__ out)
{
    __shared__ float smem[4][2][SLICE];        // 64 KB static

    const int tid       = threadIdx.x;
    const int wave      = tid >> 6;
    const int lane      = tid & 63;
    const int traceBase = blockIdx.x * BLKT + wave * 64;

    float P = 0.0f, t_rest = -1.0f;            // folds the i==0 branch

    // Fire 32 global_load_lds for chunk starting at column ccol into buffer b.
    // LDS dest: uniform base (slot k*64) + lane*4 (hardware). Global source:
    // pre-swizzled per-lane address so slot s holds (row=s>>5, col=(s&31)^(row&31)).
    auto stage = [&](int ccol, int b) {
        #pragma unroll
        for (int k = 0; k < 32; ++k) {
            const int s_  = k * 64 + lane;
            const int row = s_ >> 5;
            const int col = (s_ & 31) ^ (row & 31);
            int gc = ccol + col;
            if (gc > 400) gc = 400;            // tail clamp (dup read, discarded)
            const float* gp = S + (traceBase + row) * L_STEPS + gc;
            __builtin_amdgcn_global_load_lds(
                (gas1_t)gp, (las3_t)&smem[wave][b][k * 64], 4, 0, 0);
        }
    };

    stage(0, 0);
    asm volatile("s_waitcnt vmcnt(0)" ::: "memory");   // chunk 0 ready

    #pragma unroll 1
    for (int c = 0; c < NCHUNK; ++c) {
        const int c0 = c * CHUNK;
        const int b  = c & 1;

        // Steady state queue at this point: [gll_c(32), stores_{c-1}(32)].
        // Wait for gll_c; leave the 32 stores in flight (counted, T4).
        if (c) asm volatile("s_waitcnt vmcnt(32)" ::: "memory");

        // ---- read own row's 32 inputs (swizzled, 2-way = free) ----
        float sv[CHUNK];
        #pragma unroll
        for (int j = 0; j < CHUNK; ++j)
            sv[j] = smem[wave][b][lane * CHUNK + (j ^ (lane & 31))];
        asm volatile("" ::: "memory");

        // ---- issue next chunk's 32 gll: in flight across all of compute ----
        if (c + 1 < NCHUNK) stage(c0 + CHUNK, (c + 1) & 1);
        asm volatile("" ::: "memory");

        // ---- LIF scan, exact ref op order ----
        #pragma unroll
        for (int j = 0; j < CHUNK; ++j) {
            const float t = (float)(c0 + j) * 0.125f;        // exact in fp32
            float p = (t <= t_rest)
                    ? 0.0f
                    : ((P > -1.0f) ? (P + sv[j]) - 0.25f : 0.0f);
            const bool spike = (p >= 25.0f);
            t_rest = spike ? t + 5.0f : t_rest;              // exact in fp32
            p      = spike ? p + 4.0f : p;
            sv[j]  = p;
            P      = p;
        }

        // ---- write results back (same swizzle, free) ----
        #pragma unroll
        for (int j = 0; j < CHUNK; ++j)
            smem[wave][b][lane * CHUNK + (j ^ (lane & 31))] = sv[j];
        asm volatile("" ::: "memory");

        // ---- store chunk c: linear LDS read (free), fire-and-forget global ----
        #pragma unroll
        for (int k = 0; k < 32; ++k) {
            const int s_  = k * 64 + lane;
            const int row = s_ >> 5;
            const int col = (s_ & 31) ^ (row & 31);
            const int gc  = c0 + col;
            if (gc < L_STEPS)
                out[(traceBase + row) * L_STEPS + gc] = smem[wave][b][s_];
        }
        asm volatile("" ::: "memory");
    }
}

extern "C" void kernel_launch(void* const* d_in, const int* in_sizes, int n_in,
                              void* d_out, int out_size, void* d_ws, size_t ws_size,
                              hipStream_t stream)
{
    // d_in[0] = Pn (dead in reference), d_in[1] = S
    const float* S   = (const float*)d_in[1];
    float*       out = (float*)d_out;

    snn_scan_kernel<<<(131072 / BLKT), BLKT, 0, stream>>>(S, out);
}